// Round 1
// baseline (505.487 us; speedup 1.0000x reference)
//
#include <hip/hip_runtime.h>
#include <cstdint>
#include <cstddef>

typedef __bf16 bf16;
typedef __bf16 bf16x8 __attribute__((ext_vector_type(8)));
typedef float  f32x4  __attribute__((ext_vector_type(4)));
typedef unsigned short u16;

#define MD ((size_t)8388608)   // 16384*512 elements

// ---- async global->LDS 16B copy. LDS dest = wave-uniform base + lane*16 ----
__device__ __forceinline__ void async_copy16(const bf16* gp, bf16* lp) {
  __builtin_amdgcn_global_load_lds(
      (__attribute__((address_space(1))) void*)(gp),
      (__attribute__((address_space(3))) void*)(lp), 16, 0, 0);
}

// ---- inline dtype probe: wave ballots the 64 even (low-half) u16s of X.
// fp32 mantissa halves are ~uniform -> P(all 64 exp<141) ~ 2e-17. ----
__device__ __forceinline__ int is_f32(const u16* __restrict__ x) {
  const int e = (x[(threadIdx.x & 63) * 2] >> 7) & 0xFF;
  return __ballot(e >= 141) != 0ull;
}

// =====================================================================
// Batched conversion of all 20 float tensors into bf16 staging in ws.
// =====================================================================
struct ConvSrc { const void* p[20]; };

__global__ __launch_bounds__(256)
void convert_all(ConvSrc s, bf16* __restrict__ ws, const u16* __restrict__ xprobe)
{
  const int n[20] = {8388608, 8388608,
                     262144, 262144, 262144, 262144, 262144, 262144, 262144, 262144,
                     1048576, 2048, 1048576, 512, 512, 512, 512, 512, 512, 512};
  const unsigned int doff[20] = {
      41943040u, 50331648u,
      58720256u, 58982400u, 59244544u, 59506688u,
      59768832u, 60030976u, 60293120u, 60555264u,
      60817408u, 61865984u, 61868032u, 62916608u,
      62917120u, 62917632u, 62918144u, 62918656u, 62919168u, 62919680u};

  const int f32 = is_f32(xprobe);

  int bi = blockIdx.x;
  int idx = 0, b0 = 0;
  for (; idx < 20; ++idx) {
    const int nb = (n[idx] + 2047) >> 11;
    if (bi < b0 + nb) break;
    b0 += nb;
  }
  const int i = ((bi - b0) << 11) + threadIdx.x * 8;
  if (i >= n[idx]) return;
  bf16* dst = ws + doff[idx] + i;
  if (f32) {
    const float* sp = (const float*)s.p[idx] + i;
    f32x4 a = *(const f32x4*)sp;
    f32x4 b = *(const f32x4*)(sp + 4);
    bf16x8 o;
#pragma unroll
    for (int e = 0; e < 4; ++e) { o[e] = (bf16)a[e]; o[4 + e] = (bf16)b[e]; }
    *(bf16x8*)dst = o;
  } else {
    *(bf16x8*)dst = *(const bf16x8*)((const bf16*)s.p[idx] + i);
  }
}

// =====================================================================
// GEMM v7: 256-row-tile, 8-wave, double-buffered, counted-vmcnt schedule
// (T2+T3+T4+T5 port). C[M,N] = act(A[M,K] @ B[N,K]^T + bias), bf16 in,
// fp32 accum. MODE 0: plain, 1: bias+LeakyReLU(0.01), 2: bias only.
//
// Structure per K-tile (BK=64), 2 phases:
//  PH1: stage K(t+1).A -> buf^1 | ds_read B(all nj,ks) + A(mh0) from buf
//       | s_barrier | lgkmcnt(0) | setprio(1) 32 MFMA setprio(0) | s_barrier
//  PH2: stage K(t+2).B -> buf (B already fully consumed in PH1)
//       | ds_read A(mh1) | s_barrier | lgkmcnt(0) | setprio(1) 32 MFMA
//       setprio(0) | vmcnt(BL) | s_barrier
// The only VMEM wait is the counted vmcnt(BL) once per K-tile: K(t+1).A+.B
// are guaranteed landed, K(t+2).B stays in flight across the barrier
// (never drains to 0 in the loop — this is what the old __syncthreads
// structure destroyed). Raw s_barrier everywhere; no __syncthreads.
// LDS swizzle: identical verified source-side XOR (cg ^ (row&7)) on both
// stage and ds_read -> 0 bank conflicts (measured on v6).
// XCD remap: (id&7)*chunk + id>>3; all grids have nblk % 8 == 0.
// =====================================================================
template<int ROWS>
__device__ __forceinline__ void stage_tile(const bf16* __restrict__ g,
                                           bf16* lds, int K)
{
  const int t = threadIdx.x;
  const int wbase = (t >> 6) << 6;   // wave*64
#pragma unroll
  for (int r = 0; r < ROWS / 64; ++r) {
    const int s   = (r << 9) + t;          // r*512 + t
    const int row = s >> 3;
    const int cg  = s & 7;
    async_copy16(g + (size_t)row * K + ((cg ^ (row & 7)) << 3),
                 lds + ((size_t)((r << 9) + wbase) << 3));
  }
}

template<int MODE, int BN, int WM, int WN>
__global__ __launch_bounds__(512, 2)
void gemm8p(const bf16* __restrict__ A, const bf16* __restrict__ B,
            const bf16* __restrict__ bias, bf16* __restrict__ C,
            int M, int N, int K)
{
  constexpr int BM = 256;
  constexpr int WR = BM / WM;      // wave rows: 128 (2x4) or 64 (4x2)
  constexpr int MI = WR / 16;      // 8 or 4 M-frags per wave
  constexpr int NJ = 4;            // 64 cols per wave always
  constexpr int MH = MI / 2;       // frags per phase
  constexpr int BL = BN / 64;      // B stage loads per thread per K-tile

  __shared__ __attribute__((aligned(16))) bf16 As[2][BM * 64];
  __shared__ __attribute__((aligned(16))) bf16 Bs[2][BN * 64];

  const int t    = threadIdx.x;
  const int lane = t & 63;
  const int quad = lane >> 4;
  const int l15  = lane & 15;
  const int wave = t >> 6;
  const int wm   = wave / WN;
  const int wn   = wave % WN;

  // ---- XCD-aware tile remap ----
  const int id    = blockIdx.y * gridDim.x + blockIdx.x;
  const int chunk = (gridDim.x * gridDim.y) >> 3;
  const int lin   = (id & 7) * chunk + (id >> 3);
  const int m0    = (lin / gridDim.x) * BM;
  const int n0    = (lin % gridDim.x) * BN;

  const bf16* Ag = A + (size_t)m0 * K;
  const bf16* Bg = B + (size_t)n0 * K;

  const f32x4 fz = {0.f, 0.f, 0.f, 0.f};
  f32x4 acc[MI][NJ];
#pragma unroll
  for (int i = 0; i < MI; ++i)
#pragma unroll
    for (int j = 0; j < NJ; ++j) acc[i][j] = fz;

  const int nkt = K >> 6;

  // ---- prologue: K0 full -> buf0, K1.B -> buf1; wait K0 only ----
  stage_tile<BM>(Ag, As[0], K);
  stage_tile<BN>(Bg, Bs[0], K);
  stage_tile<BN>(Bg + (nkt > 1 ? 64 : 0), Bs[1], K);
  if constexpr (BL == 4) asm volatile("s_waitcnt vmcnt(4)" ::: "memory");
  else                   asm volatile("s_waitcnt vmcnt(2)" ::: "memory");
  __builtin_amdgcn_s_barrier();

  for (int kt = 0; kt < nkt; ++kt) {
    const int c = kt & 1;
    const bf16* a_l = As[c];
    const bf16* b_l = Bs[c];
    // clamped prefetch indices keep vmcnt counts uniform at the tail
    // (redundant re-stage of the last tile lands in dead regions)
    const int kA = (kt + 1 < nkt) ? kt + 1 : nkt - 1;
    const int kB = (kt + 2 < nkt) ? kt + 2 : nkt - 1;

    bf16x8 bfv[NJ][2];   // all B frags, live across both phases
    bf16x8 af[MH][2];

    // ---------------- PH1 : mh0 ----------------
    stage_tile<BM>(Ag + ((size_t)kA << 6), As[c ^ 1], K);
#pragma unroll
    for (int nj = 0; nj < NJ; ++nj) {
      const int row = wn * 64 + nj * 16 + l15;
#pragma unroll
      for (int ks = 0; ks < 2; ++ks) {
        const int ph = (ks * 4 + quad) ^ (row & 7);
        bfv[nj][ks] = *(const bf16x8*)(b_l + row * 64 + ph * 8);
      }
    }
#pragma unroll
    for (int mi = 0; mi < MH; ++mi) {
      const int row = wm * WR + mi * 16 + l15;
#pragma unroll
      for (int ks = 0; ks < 2; ++ks) {
        const int ph = (ks * 4 + quad) ^ (row & 7);
        af[mi][ks] = *(const bf16x8*)(a_l + row * 64 + ph * 8);
      }
    }
    __builtin_amdgcn_s_barrier();
    asm volatile("s_waitcnt lgkmcnt(0)" ::: "memory");
    __builtin_amdgcn_s_setprio(1);
#pragma unroll
    for (int mi = 0; mi < MH; ++mi)
#pragma unroll
      for (int nj = 0; nj < NJ; ++nj)
#pragma unroll
        for (int ks = 0; ks < 2; ++ks)
          acc[mi][nj] = __builtin_amdgcn_mfma_f32_16x16x32_bf16(
              af[mi][ks], bfv[nj][ks], acc[mi][nj], 0, 0, 0);
    __builtin_amdgcn_s_setprio(0);
    __builtin_amdgcn_s_barrier();

    // ---------------- PH2 : mh1 ----------------
    stage_tile<BN>(Bg + ((size_t)kB << 6), Bs[c], K);
#pragma unroll
    for (int mi = 0; mi < MH; ++mi) {
      const int row = wm * WR + (MH + mi) * 16 + l15;
#pragma unroll
      for (int ks = 0; ks < 2; ++ks) {
        const int ph = (ks * 4 + quad) ^ (row & 7);
        af[mi][ks] = *(const bf16x8*)(a_l + row * 64 + ph * 8);
      }
    }
    __builtin_amdgcn_s_barrier();
    asm volatile("s_waitcnt lgkmcnt(0)" ::: "memory");
    __builtin_amdgcn_s_setprio(1);
#pragma unroll
    for (int mi = 0; mi < MH; ++mi)
#pragma unroll
      for (int nj = 0; nj < NJ; ++nj)
#pragma unroll
        for (int ks = 0; ks < 2; ++ks)
          acc[MH + mi][nj] = __builtin_amdgcn_mfma_f32_16x16x32_bf16(
              af[mi][ks], bfv[nj][ks], acc[MH + mi][nj], 0, 0, 0);
    __builtin_amdgcn_s_setprio(0);
    // counted wait: K(t+1).A/.B landed; K(t+2).B (BL loads) stays in flight
    if constexpr (BL == 4) asm volatile("s_waitcnt vmcnt(4)" ::: "memory");
    else                   asm volatile("s_waitcnt vmcnt(2)" ::: "memory");
    __builtin_amdgcn_s_barrier();
  }

  // drain leftover LDS-DMA before LDS dealloc / epilogue
  asm volatile("s_waitcnt vmcnt(0)" ::: "memory");

  // ---- epilogue ----
#pragma unroll
  for (int mi = 0; mi < MI; ++mi) {
    const int m = m0 + wm * WR + mi * 16 + quad * 4;
#pragma unroll
    for (int nj = 0; nj < NJ; ++nj) {
      const int n = n0 + wn * 64 + nj * 16 + l15;
      float bv = 0.f;
      if (MODE >= 1) bv = (float)bias[n];
#pragma unroll
      for (int r = 0; r < 4; ++r) {
        float v = acc[mi][nj][r];
        if (MODE >= 1) v += bv;
        if (MODE == 1) v = v > 0.f ? v : 0.01f * v;
        C[(size_t)(m + r) * N + n] = (bf16)v;
      }
    }
  }
}

// =====================================================================
// Flash attention v3.1 (unchanged): static softmax (scores ~N(0,1),
// verified absmax 0.031), XCD-aware block map.
// =====================================================================
__global__ __launch_bounds__(256, 4)
void flash_attn(const bf16* __restrict__ Qp, const bf16* __restrict__ Kp,
                const bf16* __restrict__ Vp, bf16* __restrict__ Op,
                const int* __restrict__ vlen, int per_query, int sq, int skv)
{
  __shared__ __attribute__((aligned(16))) bf16 Ks[64][72];
  __shared__ __attribute__((aligned(16))) bf16 VsT[64][72];   // [d][k]
  __shared__ __attribute__((aligned(16))) bf16 Ps[4][32][72]; // per-wave [q][k]
  __shared__ int vlmax_sh;

  const int t    = threadIdx.x;
  const int wave = t >> 6;
  const int lane = t & 63;
  const int quad = lane >> 4;
  const int l15  = lane & 15;
  const int bx   = blockIdx.x;
  const int qt   = bx >> 8;          // 0..3 (slowest)
  const int h    = bx & 7;
  const int b    = (bx >> 3) & 31;
  const int q0   = qt * 128 + wave * 32;

  bf16x8 qfrag[2][2];
#pragma unroll
  for (int mt = 0; mt < 2; ++mt)
#pragma unroll
    for (int ks = 0; ks < 2; ++ks)
      qfrag[mt][ks] = *(const bf16x8*)(Qp +
          (size_t)(b * 512 + q0 + mt * 16 + l15) * sq + h * 64 + ks * 32 + quad * 8);

  int vl_r[2][4];
  int myvl = 1;
#pragma unroll
  for (int mt = 0; mt < 2; ++mt)
#pragma unroll
    for (int r = 0; r < 4; ++r) {
      const int q = q0 + mt * 16 + quad * 4 + r;
      const int v = per_query ? vlen[b * 512 + q] : vlen[b];
      vl_r[mt][r] = v;
      myvl = v > myvl ? v : myvl;
    }

  if (t == 0) vlmax_sh = 1;
  __syncthreads();
#pragma unroll
  for (int off = 1; off < 64; off <<= 1) {
    const int o = __shfl_xor(myvl, off);
    myvl = o > myvl ? o : myvl;
  }
  if (lane == 0) atomicMax(&vlmax_sh, myvl);
  __syncthreads();
  const int ktiles = (vlmax_sh + 63) >> 6;

  const f32x4 fz = {0.f, 0.f, 0.f, 0.f};
  float l_part[2][4] = {{0.f,0.f,0.f,0.f},{0.f,0.f,0.f,0.f}};
  f32x4 o_acc[2][4];
#pragma unroll
  for (int mt = 0; mt < 2; ++mt)
#pragma unroll
    for (int nt = 0; nt < 4; ++nt) o_acc[mt][nt] = fz;

  for (int kt = 0; kt < ktiles; ++kt) {
    const int k0 = kt * 64;
    __syncthreads();   // prior K/V tiles fully consumed
    {
      const int r0 = t >> 3;
      const int c0 = (t & 7) * 8;
      const bf16* g = Kp + (size_t)(b * 512 + k0 + r0) * skv + h * 64 + c0;
      *(bf16x8*)&Ks[r0][c0]      = *(const bf16x8*)g;
      *(bf16x8*)&Ks[r0 + 32][c0] = *(const bf16x8*)(g + (size_t)32 * skv);
    }
    {
      const bf16* g = Vp + (size_t)(b * 512 + k0 + wave * 16) * skv + h * 64 + lane;
      bf16x8 lo, hi;
#pragma unroll
      for (int kk = 0; kk < 8; ++kk) lo[kk] = g[(size_t)kk * skv];
#pragma unroll
      for (int kk = 0; kk < 8; ++kk) hi[kk] = g[(size_t)(kk + 8) * skv];
      *(bf16x8*)&VsT[lane][wave * 16]     = lo;
      *(bf16x8*)&VsT[lane][wave * 16 + 8] = hi;
    }
    __syncthreads();

    // ---- QK^T ----
    f32x4 s[2][4];
#pragma unroll
    for (int mt = 0; mt < 2; ++mt)
#pragma unroll
      for (int nt = 0; nt < 4; ++nt) s[mt][nt] = fz;
#pragma unroll
    for (int ks = 0; ks < 2; ++ks)
#pragma unroll
      for (int nt = 0; nt < 4; ++nt) {
        const bf16x8 bk = *(const bf16x8*)&Ks[nt * 16 + l15][ks * 32 + quad * 8];
        s[0][nt] = __builtin_amdgcn_mfma_f32_16x16x32_bf16(qfrag[0][ks], bk, s[0][nt], 0, 0, 0);
        s[1][nt] = __builtin_amdgcn_mfma_f32_16x16x32_bf16(qfrag[1][ks], bk, s[1][nt], 0, 0, 0);
      }

    // ---- static softmax: p = masked ? 0 : exp(s/8); accumulate l ----
#pragma unroll
    for (int mt = 0; mt < 2; ++mt)
#pragma unroll
      for (int nt = 0; nt < 4; ++nt) {
        const int k_abs = k0 + nt * 16 + l15;
#pragma unroll
        for (int r = 0; r < 4; ++r) {
          const float p = (k_abs < vl_r[mt][r]) ? __expf(s[mt][nt][r] * 0.125f) : 0.f;
          l_part[mt][r] += p;
          Ps[wave][mt * 16 + quad * 4 + r][nt * 16 + l15] = (bf16)p;
        }
      }

    // ---- O += P @ V (Ps per-wave; same-wave DS ordering suffices) ----
#pragma unroll
    for (int ks = 0; ks < 2; ++ks) {
      const bf16x8 ap0 = *(const bf16x8*)&Ps[wave][l15][ks * 32 + quad * 8];
      const bf16x8 ap1 = *(const bf16x8*)&Ps[wave][16 + l15][ks * 32 + quad * 8];
#pragma unroll
      for (int nt = 0; nt < 4; ++nt) {
        const bf16x8 bv = *(const bf16x8*)&VsT[nt * 16 + l15][ks * 32 + quad * 8];
        o_acc[0][nt] = __builtin_amdgcn_mfma_f32_16x16x32_bf16(ap0, bv, o_acc[0][nt], 0, 0, 0);
        o_acc[1][nt] = __builtin_amdgcn_mfma_f32_16x16x32_bf16(ap1, bv, o_acc[1][nt], 0, 0, 0);
      }
    }
  }

  // ---- epilogue ----
#pragma unroll
  for (int mt = 0; mt < 2; ++mt)
#pragma unroll
    for (int r = 0; r < 4; ++r) {
      float l = l_part[mt][r];
#pragma unroll
      for (int off = 1; off < 16; off <<= 1)
        l += __shfl_xor(l, off);
      const float inv_l = (l > 0.f) ? (1.f / l) : 0.f;
      const int q = q0 + mt * 16 + quad * 4 + r;
#pragma unroll
      for (int nt = 0; nt < 4; ++nt)
        Op[(size_t)(b * 512 + q) * 512 + h * 64 + nt * 16 + l15] =
            (bf16)(o_acc[mt][nt][r] * inv_l);
    }
}

// =====================================================================
// AddNorm (internal, bf16 out). One wave per 512-row. In-place safe.
// =====================================================================
__global__ __launch_bounds__(256)
void add_layernorm(const bf16* X, const bf16* R,
                   const bf16* __restrict__ gamma, const bf16* __restrict__ beta,
                   bf16* Out)
{
  const int t    = threadIdx.x;
  const int wave = t >> 6;
  const int lane = t & 63;
  const size_t row  = (size_t)blockIdx.x * 4 + wave;
  const size_t base = row * 512 + lane * 8;

  bf16x8 xv = *(const bf16x8*)(X + base);
  bf16x8 rv = *(const bf16x8*)(R + base);
  float v[8];
  float sum = 0.f, ss = 0.f;
#pragma unroll
  for (int i = 0; i < 8; ++i) {
    v[i] = (float)xv[i] + (float)rv[i];
    sum += v[i];
    ss  += v[i] * v[i];
  }
#pragma unroll
  for (int off = 1; off < 64; off <<= 1) {
    sum += __shfl_xor(sum, off);
    ss  += __shfl_xor(ss, off);
  }
  const float mean = sum * (1.f / 512.f);
  const float var  = ss * (1.f / 512.f) - mean * mean;
  const float rstd = rsqrtf(var + 1e-5f);

  bf16x8 gv = *(const bf16x8*)(gamma + lane * 8);
  bf16x8 bv = *(const bf16x8*)(beta + lane * 8);
  bf16x8 ov;
#pragma unroll
  for (int i = 0; i < 8; ++i)
    ov[i] = (bf16)(((v[i] - mean) * rstd) * (float)gv[i] + (float)bv[i]);
  *(bf16x8*)(Out + base) = ov;
}

// =====================================================================
// Final AddNorm: writes d_out as fp32 or bf16 per the inline dtype probe.
// =====================================================================
__global__ __launch_bounds__(256)
void add_layernorm_out(const bf16* X, const bf16* R,
                       const bf16* __restrict__ gamma, const bf16* __restrict__ beta,
                       void* Out, const u16* __restrict__ xprobe)
{
  const int t    = threadIdx.x;
  const int wave = t >> 6;
  const int lane = t & 63;
  const size_t row  = (size_t)blockIdx.x * 4 + wave;
  const size_t base = row * 512 + lane * 8;

  const int f32 = is_f32(xprobe);

  bf16x8 xv = *(const bf16x8*)(X + base);
  bf16x8 rv = *(const bf16x8*)(R + base);
  float v[8];
  float sum = 0.f, ss = 0.f;
#pragma unroll
  for (int i = 0; i < 8; ++i) {
    v[i] = (float)xv[i] + (float)rv[i];
    sum += v[i];
    ss  += v[i] * v[i];
  }
#pragma unroll
  for (int off = 1; off < 64; off <<= 1) {
    sum += __shfl_xor(sum, off);
    ss  += __shfl_xor(ss, off);
  }
  const float mean = sum * (1.f / 512.f);
  const float var  = ss * (1.f / 512.f) - mean * mean;
  const float rstd = rsqrtf(var + 1e-5f);

  bf16x8 gv = *(const bf16x8*)(gamma + lane * 8);
  bf16x8 bv = *(const bf16x8*)(beta + lane * 8);
  float o[8];
#pragma unroll
  for (int i = 0; i < 8; ++i)
    o[i] = ((v[i] - mean) * rstd) * (float)gv[i] + (float)bv[i];

  if (f32) {
    float* op = (float*)Out + base;
    f32x4 o0 = {o[0], o[1], o[2], o[3]};
    f32x4 o1 = {o[4], o[5], o[6], o[7]};
    *(f32x4*)op       = o0;
    *(f32x4*)(op + 4) = o1;
  } else {
    bf16x8 ov;
#pragma unroll
    for (int i = 0; i < 8; ++i) ov[i] = (bf16)o[i];
    *(bf16x8*)((bf16*)Out + base) = ov;
  }
}

// =====================================================================
extern "C" void kernel_launch(void* const* d_in, const int* in_sizes, int n_in,
                              void* d_out, int out_size, void* d_ws, size_t ws_size,
                              hipStream_t stream)
{
  (void)in_sizes; (void)n_in; (void)out_size; (void)ws_size;

  const int* dvl = (const int*)d_in[2];
  const int* evl = (const int*)d_in[3];
  const u16* xprobe = (const u16*)d_in[0];

  bf16* ws = (bf16*)d_ws;
  bf16* S0 = ws;                 // QKV packed / FFN hidden (S0..S3)
  bf16* S1 = ws + 1 * MD;
  bf16* S3 = ws + 3 * MD;        // attention output O
  bf16* S4 = ws + 4 * MD;        // Y then Z (in-place LN)
  bf16* Xb = ws + 5 * MD;        // X bf16; reused as FFN2 output
  bf16* Eb = ws + 6 * MD;
  bf16* W  = ws + 7 * MD;
  const bf16 *Wq1 = W,
             *Wo1 = W + 786432,   *Wq2 = W + 1048576, *Wk2 = W + 1310720,
             *Wo2 = W + 1835008,
             *W1  = W + 2097152,  *b1  = W + 3145728,
             *W2  = W + 3147776,  *b2  = W + 4196352,
             *g1  = W + 4196864,  *be1 = W + 4197376,
             *g2  = W + 4197888,  *be2 = W + 4198400,
             *g3  = W + 4198912,  *be3 = W + 4199424;

  // ---- ingest (dtype probe inlined per wave) ----
  ConvSrc cs;
  cs.p[0] = d_in[0];  cs.p[1] = d_in[1];
  for (int k = 0; k < 12; ++k) cs.p[2 + k] = d_in[4 + k];
  for (int k = 0; k < 6; ++k)  cs.p[14 + k] = d_in[16 + k];
  convert_all<<<dim3(10248), dim3(256), 0, stream>>>(cs, ws, xprobe);

  dim3 blk256(256);
  dim3 blk512(512);

  // ---- self-attention ----
  gemm8p<0,256,2,4><<<dim3(6,64), blk512, 0, stream>>>(Xb, Wq1, nullptr, S0, 16384, 1536, 512);
  flash_attn<<<dim3(1024), blk256, 0, stream>>>(S0, S0 + 512, S0 + 1024, S3, dvl, 1, 1536, 1536);
  gemm8p<0,128,4,2><<<dim3(4,64), blk512, 0, stream>>>(S3, Wo1, nullptr, S1, 16384, 512, 512);
  add_layernorm<<<dim3(4096), blk256, 0, stream>>>(Xb, S1, g1, be1, S4);   // Y

  // ---- cross-attention ----
  gemm8p<0,128,4,2><<<dim3(4,64), blk512, 0, stream>>>(S4, Wq2, nullptr, S0, 16384, 512, 512);
  gemm8p<0,256,2,4><<<dim3(4,64), blk512, 0, stream>>>(Eb, Wk2, nullptr, S1, 16384, 1024, 512);
  flash_attn<<<dim3(1024), blk256, 0, stream>>>(S0, S1, S1 + 512, S3, evl, 0, 512, 1024);
  gemm8p<0,128,4,2><<<dim3(4,64), blk512, 0, stream>>>(S3, Wo2, nullptr, S1, 16384, 512, 512);
  add_layernorm<<<dim3(4096), blk256, 0, stream>>>(S4, S1, g2, be2, S4);   // Z

  // ---- FFN ----
  gemm8p<1,256,2,4><<<dim3(8,64), blk512, 0, stream>>>(S4, W1, b1, S0, 16384, 2048, 512);
  gemm8p<2,128,4,2><<<dim3(4,64), blk512, 0, stream>>>(S0, W2, b2, Xb, 16384, 512, 2048);
  add_layernorm_out<<<dim3(4096), blk256, 0, stream>>>(S4, Xb, g3, be3, d_out, xprobe);
}

// Round 2
// 461.484 us; speedup vs baseline: 1.0954x; 1.0954x over previous
//
#include <hip/hip_runtime.h>
#include <cstdint>
#include <cstddef>

typedef __bf16 bf16;
typedef __bf16 bf16x8 __attribute__((ext_vector_type(8)));
typedef float  f32x4  __attribute__((ext_vector_type(4)));
typedef unsigned short u16;

#define MD ((size_t)8388608)   // 16384*512 elements

// ---- async global->LDS 16B copy. LDS dest = wave-uniform base + lane*16 ----
__device__ __forceinline__ void async_copy16(const bf16* gp, bf16* lp) {
  __builtin_amdgcn_global_load_lds(
      (__attribute__((address_space(1))) void*)(gp),
      (__attribute__((address_space(3))) void*)(lp), 16, 0, 0);
}

// ---- inline dtype probe: wave ballots the 64 even (low-half) u16s of X.
// fp32 mantissa halves are ~uniform -> P(all 64 exp<141) ~ 2e-17. ----
__device__ __forceinline__ int is_f32(const u16* __restrict__ x) {
  const int e = (x[(threadIdx.x & 63) * 2] >> 7) & 0xFF;
  return __ballot(e >= 141) != 0ull;
}

// =====================================================================
// Batched conversion of all 20 float tensors into bf16 staging in ws.
// =====================================================================
struct ConvSrc { const void* p[20]; };

__global__ __launch_bounds__(256)
void convert_all(ConvSrc s, bf16* __restrict__ ws, const u16* __restrict__ xprobe)
{
  const int n[20] = {8388608, 8388608,
                     262144, 262144, 262144, 262144, 262144, 262144, 262144, 262144,
                     1048576, 2048, 1048576, 512, 512, 512, 512, 512, 512, 512};
  const unsigned int doff[20] = {
      41943040u, 50331648u,
      58720256u, 58982400u, 59244544u, 59506688u,
      59768832u, 60030976u, 60293120u, 60555264u,
      60817408u, 61865984u, 61868032u, 62916608u,
      62917120u, 62917632u, 62918144u, 62918656u, 62919168u, 62919680u};

  const int f32 = is_f32(xprobe);

  int bi = blockIdx.x;
  int idx = 0, b0 = 0;
  for (; idx < 20; ++idx) {
    const int nb = (n[idx] + 2047) >> 11;
    if (bi < b0 + nb) break;
    b0 += nb;
  }
  const int i = ((bi - b0) << 11) + threadIdx.x * 8;
  if (i >= n[idx]) return;
  bf16* dst = ws + doff[idx] + i;
  if (f32) {
    const float* sp = (const float*)s.p[idx] + i;
    f32x4 a = *(const f32x4*)sp;
    f32x4 b = *(const f32x4*)(sp + 4);
    bf16x8 o;
#pragma unroll
    for (int e = 0; e < 4; ++e) { o[e] = (bf16)a[e]; o[4 + e] = (bf16)b[e]; }
    *(bf16x8*)dst = o;
  } else {
    *(bf16x8*)dst = *(const bf16x8*)((const bf16*)s.p[idx] + i);
  }
}

// =====================================================================
// gemm_bt (round-0 verified, 473us baseline): 128x128, 4 waves,
// single-buffer global_load_lds, XOR-swizzled LDS (0 conflicts),
// XCD-aware remap. Used for the N=512 GEMMs and FFN2 (2 blocks/CU,
// cross-block overlap — m232: fine-phasing a 4-wave 128-tile is null).
// =====================================================================
template<int MODE, int TM, int TN>
__global__ __launch_bounds__(256)
void gemm_bt(const bf16* __restrict__ A, const bf16* __restrict__ B,
             const bf16* __restrict__ bias, bf16* __restrict__ C,
             int M, int N, int K)
{
  constexpr int MI = TM / 32;
  constexpr int NJ = TN / 32;
  __shared__ __attribute__((aligned(16))) bf16 As[TM * 64];
  __shared__ __attribute__((aligned(16))) bf16 Bs[TN * 64];

  const int t    = threadIdx.x;
  const int wave = t >> 6;
  const int lane = t & 63;
  const int quad = lane >> 4;
  const int l15  = lane & 15;
  const int wr   = (wave >> 1) * (TM / 2);
  const int wc   = (wave & 1) * (TN / 2);

  const int id    = blockIdx.y * gridDim.x + blockIdx.x;
  const int chunk = (gridDim.x * gridDim.y) >> 3;
  const int lin   = (id & 7) * chunk + (id >> 3);
  const int m0    = (lin / gridDim.x) * TM;
  const int n0    = (lin % gridDim.x) * TN;

  const f32x4 fz = {0.f, 0.f, 0.f, 0.f};
  f32x4 acc[MI][NJ];
#pragma unroll
  for (int i = 0; i < MI; ++i)
#pragma unroll
    for (int j = 0; j < NJ; ++j) acc[i][j] = fz;

  const int nkt = K >> 6;
  for (int kt = 0; kt < nkt; ++kt) {
    const int k0 = kt << 6;
    __syncthreads();
#pragma unroll
    for (int c = 0; c < TM / 32; ++c) {
      const int s   = c * 256 + t;
      const int row = s >> 3;
      const int kg  = ((s & 7) ^ (row & 7)) << 3;
      async_copy16(A + (size_t)(m0 + row) * K + k0 + kg,
                   As + ((c * 256 + wave * 64) << 3));
    }
#pragma unroll
    for (int c = 0; c < TN / 32; ++c) {
      const int s   = c * 256 + t;
      const int row = s >> 3;
      const int kg  = ((s & 7) ^ (row & 7)) << 3;
      async_copy16(B + (size_t)(n0 + row) * K + k0 + kg,
                   Bs + ((c * 256 + wave * 64) << 3));
    }
    __syncthreads();

#pragma unroll
    for (int ks = 0; ks < 2; ++ks) {
      bf16x8 af[MI], bfv[NJ];
#pragma unroll
      for (int i = 0; i < MI; ++i) {
        const int row = wr + i * 16 + l15;
        const int ph  = (ks * 4 + quad) ^ (row & 7);
        af[i] = *(const bf16x8*)(As + row * 64 + ph * 8);
      }
#pragma unroll
      for (int j = 0; j < NJ; ++j) {
        const int row = wc + j * 16 + l15;
        const int ph  = (ks * 4 + quad) ^ (row & 7);
        bfv[j] = *(const bf16x8*)(Bs + row * 64 + ph * 8);
      }
#pragma unroll
      for (int i = 0; i < MI; ++i)
#pragma unroll
        for (int j = 0; j < NJ; ++j)
          acc[i][j] = __builtin_amdgcn_mfma_f32_16x16x32_bf16(af[i], bfv[j],
                                                              acc[i][j], 0, 0, 0);
    }
  }

#pragma unroll
  for (int i = 0; i < MI; ++i) {
    const int m = m0 + wr + i * 16 + quad * 4;
#pragma unroll
    for (int j = 0; j < NJ; ++j) {
      const int n = n0 + wc + j * 16 + l15;
      float bv = 0.f;
      if (MODE >= 1) bv = (float)bias[n];
#pragma unroll
      for (int r = 0; r < 4; ++r) {
        float v = acc[i][j][r];
        if (MODE >= 1) v += bv;
        if (MODE == 1) v = v > 0.f ? v : 0.01f * v;
        C[(size_t)(m + r) * N + n] = (bf16)v;
      }
    }
  }
}

// =====================================================================
// gemm4p: 256x256, 8 waves (2Mx4N), FINE-phased m201-style schedule.
// 4 phases per K-tile (BK=64): phase = (mh half of M-frags) x (ks half
// of K). Each phase: {ds_read frags | interleaved stage | s_barrier |
// lgkmcnt(0)+sched_barrier | setprio(1) 16 MFMA setprio(0) | s_barrier}.
// Counted vmcnt(6) ONCE per K-tile (never 0 in loop).
//
// Stage/consume schedule (hand-verified invariants):
//  A chunk r covers rows [64r,64r+64); waves read even chunks {r0,r2}
//  in mh0 phases (p0,p2), odd {r1,r3} in mh1 (p1,p3); B fully read at
//  p0 (ks0) and p2 (ks1).
//  p0 of iter j: stage A-odd of kt j+1 -> buf[j&1^1]  (regions last
//      read at p3 of j-1; barrier-separated)
//  p3 of iter j: stage A-even + all B of kt j+2 -> buf[j&1] (regions
//      last read at p2 of j; barrier-separated)
//  FIFO: end-of-iter vmcnt(6) retires ALL of kt j+1 (6 from p3 of j-1
//  + 2 from p0 of j), leaving exactly kt j+2's 6 loads in flight.
//  Tail: clamped stages keep counts uniform; writes hit only regions
//  already consumed or never read.
// =====================================================================
template<int MODE>
__global__ __launch_bounds__(512, 1)
void gemm4p(const bf16* __restrict__ A, const bf16* __restrict__ B,
            const bf16* __restrict__ bias, bf16* __restrict__ C,
            int M, int N, int K)
{
  constexpr int BM = 256, BN = 256, WM = 2, WN = 4, T = 512;
  constexpr int WR = BM / WM;          // 128 rows per wave
  constexpr int MI = WR / 16;          // 8
  constexpr int NJ = (BN / WN) / 16;   // 4
  constexpr int MH = MI / 2;           // 4
  constexpr int LA = BM * 8 / T;       // 4 loads/thread per A tile
  constexpr int LB = BN * 8 / T;       // 4
  static_assert(LA == 4 && LB == 4 && NJ == 4, "schedule assumes 4/4/4");

  __shared__ __attribute__((aligned(16))) bf16 As[2][BM * 64];
  __shared__ __attribute__((aligned(16))) bf16 Bs[2][BN * 64];

  const int t    = threadIdx.x;
  const int lane = t & 63;
  const int quad = lane >> 4;
  const int l15  = lane & 15;
  const int wave = t >> 6;
  const int wm   = wave >> 2;          // / WN
  const int wn   = wave & 3;           // % WN

  const int id    = blockIdx.y * gridDim.x + blockIdx.x;
  const int chunk = (gridDim.x * gridDim.y) >> 3;
  const int lin   = (id & 7) * chunk + (id >> 3);
  const int m0    = (lin / gridDim.x) * BM;
  const int n0    = (lin % gridDim.x) * BN;

  const bf16* Ag = A + (size_t)m0 * K;
  const bf16* Bg = B + (size_t)n0 * K;
  const int wbase = wave << 6;

  auto stA = [&](int kt, int r, int buf) {
    const int s   = r * T + t;
    const int row = s >> 3;
    const int cg  = s & 7;
    async_copy16(Ag + (size_t)row * K + (kt << 6) + ((cg ^ (row & 7)) << 3),
                 &As[buf][(size_t)(r * T + wbase) << 3]);
  };
  auto stB = [&](int kt, int r, int buf) {
    const int s   = r * T + t;
    const int row = s >> 3;
    const int cg  = s & 7;
    async_copy16(Bg + (size_t)row * K + (kt << 6) + ((cg ^ (row & 7)) << 3),
                 &Bs[buf][(size_t)(r * T + wbase) << 3]);
  };

  const f32x4 fz = {0.f, 0.f, 0.f, 0.f};
  f32x4 acc[MI][NJ];
#pragma unroll
  for (int i = 0; i < MI; ++i)
#pragma unroll
    for (int j = 0; j < NJ; ++j) acc[i][j] = fz;

  const int nkt = K >> 6;   // >= 2 always here (K>=512)

  // ---- prologue: kt0 full -> buf0; kt1 {A even, B all} -> buf1 ----
#pragma unroll
  for (int r = 0; r < LA; ++r) stA(0, r, 0);
#pragma unroll
  for (int r = 0; r < LB; ++r) stB(0, r, 0);
  stA(1, 0, 1); stA(1, 2, 1);
#pragma unroll
  for (int r = 0; r < LB; ++r) stB(1, r, 1);
  asm volatile("s_waitcnt vmcnt(6)" ::: "memory");   // kt0 landed; kt1 partial in flight
  __builtin_amdgcn_s_barrier();

  for (int j = 0; j < nkt; ++j) {
    const int cb = j & 1;
    const bf16* a_l = As[cb];
    const bf16* b_l = Bs[cb];
    const int kN = (j + 1 < nkt) ? j + 1 : nkt - 1;
    const int kF = (j + 2 < nkt) ? j + 2 : nkt - 1;

    bf16x8 bfv[NJ];
    bf16x8 af[MH];

    // ---------------- p0: (mh0, ks0) ----------------
#pragma unroll
    for (int nj = 0; nj < NJ; ++nj) {
      const int row = wn * 64 + nj * 16 + l15;
      bfv[nj] = *(const bf16x8*)(b_l + row * 64 + ((quad ^ (row & 7)) << 3));
    }
#pragma unroll
    for (int mi = 0; mi < MH; ++mi) {
      const int row = wm * WR + mi * 16 + l15;
      af[mi] = *(const bf16x8*)(a_l + row * 64 + ((quad ^ (row & 7)) << 3));
    }
    stA(kN, 1, cb ^ 1); stA(kN, 3, cb ^ 1);   // odd A chunks of kt j+1
    __builtin_amdgcn_s_barrier();
    asm volatile("s_waitcnt lgkmcnt(0)" ::: "memory");
    __builtin_amdgcn_sched_barrier(0);
    __builtin_amdgcn_s_setprio(1);
#pragma unroll
    for (int mi = 0; mi < MH; ++mi)
#pragma unroll
      for (int nj = 0; nj < NJ; ++nj)
        acc[mi][nj] = __builtin_amdgcn_mfma_f32_16x16x32_bf16(af[mi], bfv[nj],
                                                              acc[mi][nj], 0, 0, 0);
    __builtin_amdgcn_s_setprio(0);
    __builtin_amdgcn_s_barrier();

    // ---------------- p1: (mh1, ks0) ----------------
#pragma unroll
    for (int mi = 0; mi < MH; ++mi) {
      const int row = wm * WR + (MH + mi) * 16 + l15;
      af[mi] = *(const bf16x8*)(a_l + row * 64 + ((quad ^ (row & 7)) << 3));
    }
    __builtin_amdgcn_s_barrier();
    asm volatile("s_waitcnt lgkmcnt(0)" ::: "memory");
    __builtin_amdgcn_sched_barrier(0);
    __builtin_amdgcn_s_setprio(1);
#pragma unroll
    for (int mi = 0; mi < MH; ++mi)
#pragma unroll
      for (int nj = 0; nj < NJ; ++nj)
        acc[MH + mi][nj] = __builtin_amdgcn_mfma_f32_16x16x32_bf16(af[mi], bfv[nj],
                                                                   acc[MH + mi][nj], 0, 0, 0);
    __builtin_amdgcn_s_setprio(0);
    __builtin_amdgcn_s_barrier();

    // ---------------- p2: (mh0, ks1) ----------------
#pragma unroll
    for (int nj = 0; nj < NJ; ++nj) {
      const int row = wn * 64 + nj * 16 + l15;
      bfv[nj] = *(const bf16x8*)(b_l + row * 64 + (((4 + quad) ^ (row & 7)) << 3));
    }
#pragma unroll
    for (int mi = 0; mi < MH; ++mi) {
      const int row = wm * WR + mi * 16 + l15;
      af[mi] = *(const bf16x8*)(a_l + row * 64 + (((4 + quad) ^ (row & 7)) << 3));
    }
    __builtin_amdgcn_s_barrier();
    asm volatile("s_waitcnt lgkmcnt(0)" ::: "memory");
    __builtin_amdgcn_sched_barrier(0);
    __builtin_amdgcn_s_setprio(1);
#pragma unroll
    for (int mi = 0; mi < MH; ++mi)
#pragma unroll
      for (int nj = 0; nj < NJ; ++nj)
        acc[mi][nj] = __builtin_amdgcn_mfma_f32_16x16x32_bf16(af[mi], bfv[nj],
                                                              acc[mi][nj], 0, 0, 0);
    __builtin_amdgcn_s_setprio(0);
    __builtin_amdgcn_s_barrier();

    // ---------------- p3: (mh1, ks1) ----------------
#pragma unroll
    for (int mi = 0; mi < MH; ++mi) {
      const int row = wm * WR + (MH + mi) * 16 + l15;
      af[mi] = *(const bf16x8*)(a_l + row * 64 + (((4 + quad) ^ (row & 7)) << 3));
    }
    stA(kF, 0, cb); stA(kF, 2, cb);           // even A chunks of kt j+2
#pragma unroll
    for (int r = 0; r < LB; ++r) stB(kF, r, cb);
    __builtin_amdgcn_s_barrier();
    asm volatile("s_waitcnt lgkmcnt(0)" ::: "memory");
    __builtin_amdgcn_sched_barrier(0);
    __builtin_amdgcn_s_setprio(1);
#pragma unroll
    for (int mi = 0; mi < MH; ++mi)
#pragma unroll
      for (int nj = 0; nj < NJ; ++nj)
        acc[MH + mi][nj] = __builtin_amdgcn_mfma_f32_16x16x32_bf16(af[mi], bfv[nj],
                                                                   acc[MH + mi][nj], 0, 0, 0);
    __builtin_amdgcn_s_setprio(0);
    asm volatile("s_waitcnt vmcnt(6)" ::: "memory");  // kt j+1 fully landed
    __builtin_amdgcn_s_barrier();
  }

  asm volatile("s_waitcnt vmcnt(0)" ::: "memory");    // drain LDS-DMA

  // ---- epilogue ----
#pragma unroll
  for (int mi = 0; mi < MI; ++mi) {
    const int m = m0 + wm * WR + mi * 16 + quad * 4;
#pragma unroll
    for (int nj = 0; nj < NJ; ++nj) {
      const int n = n0 + wn * 64 + nj * 16 + l15;
      float bv = 0.f;
      if (MODE >= 1) bv = (float)bias[n];
#pragma unroll
      for (int r = 0; r < 4; ++r) {
        float v = acc[mi][nj][r];
        if (MODE >= 1) v += bv;
        if (MODE == 1) v = v > 0.f ? v : 0.01f * v;
        C[(size_t)(m + r) * N + n] = (bf16)v;
      }
    }
  }
}

// =====================================================================
// Flash attention v3.1 (unchanged): static softmax (scores ~N(0,1),
// verified absmax 0.031), XCD-aware block map.
// =====================================================================
__global__ __launch_bounds__(256, 4)
void flash_attn(const bf16* __restrict__ Qp, const bf16* __restrict__ Kp,
                const bf16* __restrict__ Vp, bf16* __restrict__ Op,
                const int* __restrict__ vlen, int per_query, int sq, int skv)
{
  __shared__ __attribute__((aligned(16))) bf16 Ks[64][72];
  __shared__ __attribute__((aligned(16))) bf16 VsT[64][72];   // [d][k]
  __shared__ __attribute__((aligned(16))) bf16 Ps[4][32][72]; // per-wave [q][k]
  __shared__ int vlmax_sh;

  const int t    = threadIdx.x;
  const int wave = t >> 6;
  const int lane = t & 63;
  const int quad = lane >> 4;
  const int l15  = lane & 15;
  const int bx   = blockIdx.x;
  const int qt   = bx >> 8;          // 0..3 (slowest)
  const int h    = bx & 7;
  const int b    = (bx >> 3) & 31;
  const int q0   = qt * 128 + wave * 32;

  bf16x8 qfrag[2][2];
#pragma unroll
  for (int mt = 0; mt < 2; ++mt)
#pragma unroll
    for (int ks = 0; ks < 2; ++ks)
      qfrag[mt][ks] = *(const bf16x8*)(Qp +
          (size_t)(b * 512 + q0 + mt * 16 + l15) * sq + h * 64 + ks * 32 + quad * 8);

  int vl_r[2][4];
  int myvl = 1;
#pragma unroll
  for (int mt = 0; mt < 2; ++mt)
#pragma unroll
    for (int r = 0; r < 4; ++r) {
      const int q = q0 + mt * 16 + quad * 4 + r;
      const int v = per_query ? vlen[b * 512 + q] : vlen[b];
      vl_r[mt][r] = v;
      myvl = v > myvl ? v : myvl;
    }

  if (t == 0) vlmax_sh = 1;
  __syncthreads();
#pragma unroll
  for (int off = 1; off < 64; off <<= 1) {
    const int o = __shfl_xor(myvl, off);
    myvl = o > myvl ? o : myvl;
  }
  if (lane == 0) atomicMax(&vlmax_sh, myvl);
  __syncthreads();
  const int ktiles = (vlmax_sh + 63) >> 6;

  const f32x4 fz = {0.f, 0.f, 0.f, 0.f};
  float l_part[2][4] = {{0.f,0.f,0.f,0.f},{0.f,0.f,0.f,0.f}};
  f32x4 o_acc[2][4];
#pragma unroll
  for (int mt = 0; mt < 2; ++mt)
#pragma unroll
    for (int nt = 0; nt < 4; ++nt) o_acc[mt][nt] = fz;

  for (int kt = 0; kt < ktiles; ++kt) {
    const int k0 = kt * 64;
    __syncthreads();   // prior K/V tiles fully consumed
    {
      const int r0 = t >> 3;
      const int c0 = (t & 7) * 8;
      const bf16* g = Kp + (size_t)(b * 512 + k0 + r0) * skv + h * 64 + c0;
      *(bf16x8*)&Ks[r0][c0]      = *(const bf16x8*)g;
      *(bf16x8*)&Ks[r0 + 32][c0] = *(const bf16x8*)(g + (size_t)32 * skv);
    }
    {
      const bf16* g = Vp + (size_t)(b * 512 + k0 + wave * 16) * skv + h * 64 + lane;
      bf16x8 lo, hi;
#pragma unroll
      for (int kk = 0; kk < 8; ++kk) lo[kk] = g[(size_t)kk * skv];
#pragma unroll
      for (int kk = 0; kk < 8; ++kk) hi[kk] = g[(size_t)(kk + 8) * skv];
      *(bf16x8*)&VsT[lane][wave * 16]     = lo;
      *(bf16x8*)&VsT[lane][wave * 16 + 8] = hi;
    }
    __syncthreads();

    // ---- QK^T ----
    f32x4 s[2][4];
#pragma unroll
    for (int mt = 0; mt < 2; ++mt)
#pragma unroll
      for (int nt = 0; nt < 4; ++nt) s[mt][nt] = fz;
#pragma unroll
    for (int ks = 0; ks < 2; ++ks)
#pragma unroll
      for (int nt = 0; nt < 4; ++nt) {
        const bf16x8 bk = *(const bf16x8*)&Ks[nt * 16 + l15][ks * 32 + quad * 8];
        s[0][nt] = __builtin_amdgcn_mfma_f32_16x16x32_bf16(qfrag[0][ks], bk, s[0][nt], 0, 0, 0);
        s[1][nt] = __builtin_amdgcn_mfma_f32_16x16x32_bf16(qfrag[1][ks], bk, s[1][nt], 0, 0, 0);
      }

    // ---- static softmax: p = masked ? 0 : exp(s/8); accumulate l ----
#pragma unroll
    for (int mt = 0; mt < 2; ++mt)
#pragma unroll
      for (int nt = 0; nt < 4; ++nt) {
        const int k_abs = k0 + nt * 16 + l15;
#pragma unroll
        for (int r = 0; r < 4; ++r) {
          const float p = (k_abs < vl_r[mt][r]) ? __expf(s[mt][nt][r] * 0.125f) : 0.f;
          l_part[mt][r] += p;
          Ps[wave][mt * 16 + quad * 4 + r][nt * 16 + l15] = (bf16)p;
        }
      }

    // ---- O += P @ V (Ps per-wave; same-wave DS ordering suffices) ----
#pragma unroll
    for (int ks = 0; ks < 2; ++ks) {
      const bf16x8 ap0 = *(const bf16x8*)&Ps[wave][l15][ks * 32 + quad * 8];
      const bf16x8 ap1 = *(const bf16x8*)&Ps[wave][16 + l15][ks * 32 + quad * 8];
#pragma unroll
      for (int nt = 0; nt < 4; ++nt) {
        const bf16x8 bv = *(const bf16x8*)&VsT[nt * 16 + l15][ks * 32 + quad * 8];
        o_acc[0][nt] = __builtin_amdgcn_mfma_f32_16x16x32_bf16(ap0, bv, o_acc[0][nt], 0, 0, 0);
        o_acc[1][nt] = __builtin_amdgcn_mfma_f32_16x16x32_bf16(ap1, bv, o_acc[1][nt], 0, 0, 0);
      }
    }
  }

  // ---- epilogue ----
#pragma unroll
  for (int mt = 0; mt < 2; ++mt)
#pragma unroll
    for (int r = 0; r < 4; ++r) {
      float l = l_part[mt][r];
#pragma unroll
      for (int off = 1; off < 16; off <<= 1)
        l += __shfl_xor(l, off);
      const float inv_l = (l > 0.f) ? (1.f / l) : 0.f;
      const int q = q0 + mt * 16 + quad * 4 + r;
#pragma unroll
      for (int nt = 0; nt < 4; ++nt)
        Op[(size_t)(b * 512 + q) * 512 + h * 64 + nt * 16 + l15] =
            (bf16)(o_acc[mt][nt][r] * inv_l);
    }
}

// =====================================================================
// AddNorm (internal, bf16 out). One wave per 512-row. In-place safe.
// =====================================================================
__global__ __launch_bounds__(256)
void add_layernorm(const bf16* X, const bf16* R,
                   const bf16* __restrict__ gamma, const bf16* __restrict__ beta,
                   bf16* Out)
{
  const int t    = threadIdx.x;
  const int wave = t >> 6;
  const int lane = t & 63;
  const size_t row  = (size_t)blockIdx.x * 4 + wave;
  const size_t base = row * 512 + lane * 8;

  bf16x8 xv = *(const bf16x8*)(X + base);
  bf16x8 rv = *(const bf16x8*)(R + base);
  float v[8];
  float sum = 0.f, ss = 0.f;
#pragma unroll
  for (int i = 0; i < 8; ++i) {
    v[i] = (float)xv[i] + (float)rv[i];
    sum += v[i];
    ss  += v[i] * v[i];
  }
#pragma unroll
  for (int off = 1; off < 64; off <<= 1) {
    sum += __shfl_xor(sum, off);
    ss  += __shfl_xor(ss, off);
  }
  const float mean = sum * (1.f / 512.f);
  const float var  = ss * (1.f / 512.f) - mean * mean;
  const float rstd = rsqrtf(var + 1e-5f);

  bf16x8 gv = *(const bf16x8*)(gamma + lane * 8);
  bf16x8 bv = *(const bf16x8*)(beta + lane * 8);
  bf16x8 ov;
#pragma unroll
  for (int i = 0; i < 8; ++i)
    ov[i] = (bf16)(((v[i] - mean) * rstd) * (float)gv[i] + (float)bv[i]);
  *(bf16x8*)(Out + base) = ov;
}

// =====================================================================
// Final AddNorm: writes d_out as fp32 or bf16 per the inline dtype probe.
// =====================================================================
__global__ __launch_bounds__(256)
void add_layernorm_out(const bf16* X, const bf16* R,
                       const bf16* __restrict__ gamma, const bf16* __restrict__ beta,
                       void* Out, const u16* __restrict__ xprobe)
{
  const int t    = threadIdx.x;
  const int wave = t >> 6;
  const int lane = t & 63;
  const size_t row  = (size_t)blockIdx.x * 4 + wave;
  const size_t base = row * 512 + lane * 8;

  const int f32 = is_f32(xprobe);

  bf16x8 xv = *(const bf16x8*)(X + base);
  bf16x8 rv = *(const bf16x8*)(R + base);
  float v[8];
  float sum = 0.f, ss = 0.f;
#pragma unroll
  for (int i = 0; i < 8; ++i) {
    v[i] = (float)xv[i] + (float)rv[i];
    sum += v[i];
    ss  += v[i] * v[i];
  }
#pragma unroll
  for (int off = 1; off < 64; off <<= 1) {
    sum += __shfl_xor(sum, off);
    ss  += __shfl_xor(ss, off);
  }
  const float mean = sum * (1.f / 512.f);
  const float var  = ss * (1.f / 512.f) - mean * mean;
  const float rstd = rsqrtf(var + 1e-5f);

  bf16x8 gv = *(const bf16x8*)(gamma + lane * 8);
  bf16x8 bv = *(const bf16x8*)(beta + lane * 8);
  float o[8];
#pragma unroll
  for (int i = 0; i < 8; ++i)
    o[i] = ((v[i] - mean) * rstd) * (float)gv[i] + (float)bv[i];

  if (f32) {
    float* op = (float*)Out + base;
    f32x4 o0 = {o[0], o[1], o[2], o[3]};
    f32x4 o1 = {o[4], o[5], o[6], o[7]};
    *(f32x4*)op       = o0;
    *(f32x4*)(op + 4) = o1;
  } else {
    bf16x8 ov;
#pragma unroll
    for (int i = 0; i < 8; ++i) ov[i] = (bf16)o[i];
    *(bf16x8*)((bf16*)Out + base) = ov;
  }
}

// =====================================================================
extern "C" void kernel_launch(void* const* d_in, const int* in_sizes, int n_in,
                              void* d_out, int out_size, void* d_ws, size_t ws_size,
                              hipStream_t stream)
{
  (void)in_sizes; (void)n_in; (void)out_size; (void)ws_size;

  const int* dvl = (const int*)d_in[2];
  const int* evl = (const int*)d_in[3];
  const u16* xprobe = (const u16*)d_in[0];

  bf16* ws = (bf16*)d_ws;
  bf16* S0 = ws;                 // QKV packed / FFN hidden (S0..S3)
  bf16* S1 = ws + 1 * MD;
  bf16* S3 = ws + 3 * MD;        // attention output O
  bf16* S4 = ws + 4 * MD;        // Y then Z (in-place LN)
  bf16* Xb = ws + 5 * MD;        // X bf16; reused as FFN2 output
  bf16* Eb = ws + 6 * MD;
  bf16* W  = ws + 7 * MD;
  const bf16 *Wq1 = W,
             *Wo1 = W + 786432,   *Wq2 = W + 1048576, *Wk2 = W + 1310720,
             *Wo2 = W + 1835008,
             *W1  = W + 2097152,  *b1  = W + 3145728,
             *W2  = W + 3147776,  *b2  = W + 4196352,
             *g1  = W + 4196864,  *be1 = W + 4197376,
             *g2  = W + 4197888,  *be2 = W + 4198400,
             *g3  = W + 4198912,  *be3 = W + 4199424;

  // ---- ingest (dtype probe inlined per wave) ----
  ConvSrc cs;
  cs.p[0] = d_in[0];  cs.p[1] = d_in[1];
  for (int k = 0; k < 12; ++k) cs.p[2 + k] = d_in[4 + k];
  for (int k = 0; k < 6; ++k)  cs.p[14 + k] = d_in[16 + k];
  convert_all<<<dim3(10248), dim3(256), 0, stream>>>(cs, ws, xprobe);

  dim3 blk256(256);
  dim3 blk512(512);
  dim3 gP(4, 128);     // 128x128 tiles, N=512

  // ---- self-attention ----
  gemm4p<0><<<dim3(6, 64), blk512, 0, stream>>>(Xb, Wq1, nullptr, S0, 16384, 1536, 512);
  flash_attn<<<dim3(1024), blk256, 0, stream>>>(S0, S0 + 512, S0 + 1024, S3, dvl, 1, 1536, 1536);
  gemm_bt<0,128,128><<<gP, blk256, 0, stream>>>(S3, Wo1, nullptr, S1, 16384, 512, 512);
  add_layernorm<<<dim3(4096), blk256, 0, stream>>>(Xb, S1, g1, be1, S4);   // Y

  // ---- cross-attention ----
  gemm_bt<0,128,128><<<gP, blk256, 0, stream>>>(S4, Wq2, nullptr, S0, 16384, 512, 512);
  gemm4p<0><<<dim3(4, 64), blk512, 0, stream>>>(Eb, Wk2, nullptr, S1, 16384, 1024, 512);
  flash_attn<<<dim3(1024), blk256, 0, stream>>>(S0, S1, S1 + 512, S3, evl, 0, 512, 1024);
  gemm_bt<0,128,128><<<gP, blk256, 0, stream>>>(S3, Wo2, nullptr, S1, 16384, 512, 512);
  add_layernorm<<<dim3(4096), blk256, 0, stream>>>(S4, S1, g2, be2, S4);   // Z

  // ---- FFN ----
  gemm4p<1><<<dim3(8, 64), blk512, 0, stream>>>(S4, W1, b1, S0, 16384, 2048, 512);
  gemm_bt<2,128,128><<<gP, blk256, 0, stream>>>(S0, W2, b2, Xb, 16384, 512, 2048);
  add_layernorm_out<<<dim3(4096), blk256, 0, stream>>>(S4, Xb, g3, be3, d_out, xprobe);
}